// Round 1
// baseline (517.822 us; speedup 1.0000x reference)
//
#include <hip/hip_runtime.h>
#include <hip/hip_bf16.h>

#define Bb 4
#define Cc 256
#define Nn 4096

typedef short s16x8 __attribute__((ext_vector_type(8)));
typedef float f32x4 __attribute__((ext_vector_type(4)));

__device__ __forceinline__ unsigned short f2bf(float f) {
    unsigned u = __builtin_bit_cast(unsigned, f);
    u += 0x7FFFu + ((u >> 16) & 1u);
    return (unsigned short)(u >> 16);
}

__device__ __forceinline__ f32x4 mfma16(s16x8 a, s16x8 b, f32x4 c) {
    return __builtin_amdgcn_mfma_f32_16x16x32_bf16(a, b, c, 0, 0, 0);
}

// ---------------- prep: W fp32 -> bf16 ----------------
__global__ void prep_w(const float* __restrict__ Wq, const float* __restrict__ Wk,
                       const float* __restrict__ Wv, unsigned short* __restrict__ Wbf) {
    int idx = (blockIdx.x * 256 + threadIdx.x) * 8;  // < 3*65536
    int mat = idx >> 16;
    int off = idx & 65535;
    const float* src = (mat == 0) ? Wq : ((mat == 1) ? Wk : Wv);
    float4 a = *(const float4*)(src + off);
    float4 b = *(const float4*)(src + off + 4);
    s16x8 o;
    o[0] = (short)f2bf(a.x); o[1] = (short)f2bf(a.y);
    o[2] = (short)f2bf(a.z); o[3] = (short)f2bf(a.w);
    o[4] = (short)f2bf(b.x); o[5] = (short)f2bf(b.y);
    o[6] = (short)f2bf(b.z); o[7] = (short)f2bf(b.w);
    *(s16x8*)(Wbf + idx) = o;
}

// ---------------- transpose: x[b][c][n] fp32 -> xT[b][n][c] bf16 ----------------
__global__ void transpose_x(const float* __restrict__ x, unsigned short* __restrict__ xT) {
    int b = blockIdx.z, c0 = blockIdx.y * 64, n0 = blockIdx.x * 64;
    __shared__ float tile[64][65];
    int t = threadIdx.x;
    int r = t >> 2, q = t & 3;
    const float* src = x + ((size_t)(b * Cc + c0 + r)) * Nn + n0 + q * 16;
#pragma unroll
    for (int j = 0; j < 4; j++) {
        float4 v4 = *(const float4*)(src + j * 4);
        tile[r][q * 16 + j * 4 + 0] = v4.x;
        tile[r][q * 16 + j * 4 + 1] = v4.y;
        tile[r][q * 16 + j * 4 + 2] = v4.z;
        tile[r][q * 16 + j * 4 + 3] = v4.w;
    }
    __syncthreads();
    // write rows of xT: row n = n0 + r, cols c0 + q*16 .. +15
    unsigned short* dst = xT + ((size_t)b * Nn + n0 + r) * Cc + c0 + q * 16;
    s16x8 o0, o1;
#pragma unroll
    for (int j = 0; j < 8; j++) o0[j] = (short)f2bf(tile[q * 16 + j][r]);
#pragma unroll
    for (int j = 0; j < 8; j++) o1[j] = (short)f2bf(tile[q * 16 + 8 + j][r]);
    *(s16x8*)dst = o0;
    *(s16x8*)(dst + 8) = o1;
}

// ---------------- projections ----------------
// mat 0/1: qT/kT[b][n][c_out] = sum_ci xT[b][n][ci] * W[c_out][ci] + bias[c_out]
// mat 2  : v[b][c_out][n]     = same, stored [C][N]
__global__ void proj(const unsigned short* __restrict__ xT, const unsigned short* __restrict__ Wbf,
                     const float* __restrict__ bq, const float* __restrict__ bk,
                     const float* __restrict__ bv,
                     unsigned short* __restrict__ qT, unsigned short* __restrict__ kT,
                     unsigned short* __restrict__ vO) {
    int nt0 = blockIdx.x * 64;
    int mat = blockIdx.y;
    int b   = blockIdx.z;
    int t = threadIdx.x, w = t >> 6, l = t & 63;
    int lr = l & 15, lg = l >> 4;
    const unsigned short* Wm  = Wbf + mat * (Cc * Cc);
    const float* bias = (mat == 0) ? bq : ((mat == 1) ? bk : bv);
    const unsigned short* xTb = xT + (size_t)b * Nn * Cc;

    if (mat < 2) {
        unsigned short* out = ((mat == 0) ? qT : kT) + (size_t)b * Nn * Cc;
        int nrow = nt0 + w * 16;
        s16x8 af[8];
#pragma unroll
        for (int kk = 0; kk < 8; kk++)
            af[kk] = *(const s16x8*)(xTb + (nrow + lr) * Cc + kk * 32 + lg * 8);
        for (int ct = 0; ct < 16; ct++) {
            f32x4 acca = {0, 0, 0, 0}, accb = {0, 0, 0, 0};
#pragma unroll
            for (int kk = 0; kk < 8; kk += 2) {
                s16x8 bfa = *(const s16x8*)(Wm + (ct * 16 + lr) * Cc + kk * 32 + lg * 8);
                s16x8 bfb = *(const s16x8*)(Wm + (ct * 16 + lr) * Cc + (kk + 1) * 32 + lg * 8);
                acca = mfma16(af[kk], bfa, acca);
                accb = mfma16(af[kk + 1], bfb, accb);
            }
            f32x4 acc = acca + accb;
            float bb = bias[ct * 16 + lr];
#pragma unroll
            for (int r = 0; r < 4; r++)
                out[(nrow + lg * 4 + r) * Cc + ct * 16 + lr] = f2bf(acc[r] + bb);
        }
    } else {
        unsigned short* out = vO + (size_t)b * Cc * Nn;
        for (int mt = 0; mt < 4; mt++) {
            int crow = (w * 4 + mt) * 16;
            s16x8 af[8];
#pragma unroll
            for (int kk = 0; kk < 8; kk++)
                af[kk] = *(const s16x8*)(Wm + (crow + lr) * Cc + kk * 32 + lg * 8);
#pragma unroll
            for (int nt = 0; nt < 4; nt++) {
                f32x4 acca = {0, 0, 0, 0}, accb = {0, 0, 0, 0};
#pragma unroll
                for (int kk = 0; kk < 8; kk += 2) {
                    s16x8 bfa = *(const s16x8*)(xTb + (nt0 + nt * 16 + lr) * Cc + kk * 32 + lg * 8);
                    s16x8 bfb = *(const s16x8*)(xTb + (nt0 + nt * 16 + lr) * Cc + (kk + 1) * 32 + lg * 8);
                    acca = mfma16(af[kk], bfa, acca);
                    accb = mfma16(af[kk + 1], bfb, accb);
                }
                f32x4 acc = acca + accb;
#pragma unroll
                for (int r = 0; r < 4; r++) {
                    float bb = bias[crow + lg * 4 + r];
                    out[(size_t)(crow + lg * 4 + r) * Nn + nt0 + nt * 16 + lr] = f2bf(acc[r] + bb);
                }
            }
        }
    }
}

// ---------------- fused flash attention ----------------
// per wave: 16 rows of i; E = Q^T K (16x32 per j-tile), online softmax over j,
// O^T[i][c] += P * V^T, epilogue out = gamma*O/l + x
__global__ void __launch_bounds__(256, 1)
attn(const unsigned short* __restrict__ qT, const unsigned short* __restrict__ kT,
     const unsigned short* __restrict__ vv, const float* __restrict__ x,
     const float* __restrict__ gamma, float* __restrict__ out) {
    int b = blockIdx.y;
    int t = threadIdx.x, w = t >> 6, l = t & 63;
    int lr = l & 15, lg = l >> 4;
    int i0 = blockIdx.x * 64 + w * 16;
    __shared__ unsigned short P_lds[4][512];  // per-wave [16][32] bf16
    unsigned short* pl = P_lds[w];
    const unsigned short* qb = qT + ((size_t)b * Nn + i0) * Cc;
    const unsigned short* kb = kT + (size_t)b * Nn * Cc;
    const unsigned short* vb = vv + (size_t)b * Cc * Nn;

    s16x8 qf[8];
#pragma unroll
    for (int kk = 0; kk < 8; kk++)
        qf[kk] = *(const s16x8*)(qb + lr * Cc + kk * 32 + lg * 8);

    f32x4 O[16];
#pragma unroll
    for (int ct = 0; ct < 16; ct++) O[ct] = {0, 0, 0, 0};
    float m[4]    = {-1e30f, -1e30f, -1e30f, -1e30f};
    float lsum[4] = {0, 0, 0, 0};
    const float L2E = 1.44269504088896340736f;

    for (int jt = 0; jt < 128; jt++) {
        int j0 = jt * 32;
        // ---- QK^T: E tiles (split accumulators for ILP) ----
        f32x4 E0a = {0, 0, 0, 0}, E0b = {0, 0, 0, 0}, E1a = {0, 0, 0, 0}, E1b = {0, 0, 0, 0};
#pragma unroll
        for (int kk = 0; kk < 8; kk += 2) {
            s16x8 k0a = *(const s16x8*)(kb + (j0 + lr) * Cc + kk * 32 + lg * 8);
            s16x8 k1a = *(const s16x8*)(kb + (j0 + 16 + lr) * Cc + kk * 32 + lg * 8);
            s16x8 k0b = *(const s16x8*)(kb + (j0 + lr) * Cc + (kk + 1) * 32 + lg * 8);
            s16x8 k1b = *(const s16x8*)(kb + (j0 + 16 + lr) * Cc + (kk + 1) * 32 + lg * 8);
            E0a = mfma16(qf[kk], k0a, E0a);
            E1a = mfma16(qf[kk], k1a, E1a);
            E0b = mfma16(qf[kk + 1], k0b, E0b);
            E1b = mfma16(qf[kk + 1], k1b, E1b);
        }
        f32x4 E0 = E0a + E0b, E1 = E1a + E1b;
        // ---- V loads early (independent of softmax) ----
        s16x8 vf[16];
#pragma unroll
        for (int ct = 0; ct < 16; ct++)
            vf[ct] = *(const s16x8*)(vb + (size_t)(ct * 16 + lr) * Nn + j0 + lg * 8);
        // ---- online softmax over j (rows spread r=0..3, cols over 16 lanes) ----
        float pm[4];
#pragma unroll
        for (int r = 0; r < 4; r++) pm[r] = fmaxf(E0[r], E1[r]);
#pragma unroll
        for (int r = 0; r < 4; r++) {
#pragma unroll
            for (int msk = 1; msk <= 8; msk <<= 1)
                pm[r] = fmaxf(pm[r], __shfl_xor(pm[r], msk));
        }
        bool need = (pm[0] > m[0] + 8.f) | (pm[1] > m[1] + 8.f) |
                    (pm[2] > m[2] + 8.f) | (pm[3] > m[3] + 8.f);
        if (__any(need)) {  // defer-max: rare after first tiles
#pragma unroll
            for (int r = 0; r < 4; r++) {
                float mn = fmaxf(m[r], pm[r]);
                float sc = exp2f((m[r] - mn) * L2E);
                lsum[r] *= sc;
                m[r] = mn;
#pragma unroll
                for (int ct = 0; ct < 16; ct++) O[ct][r] *= sc;
            }
        }
        float p0[4], p1[4], ps[4];
#pragma unroll
        for (int r = 0; r < 4; r++) {
            p0[r] = exp2f((E0[r] - m[r]) * L2E);
            p1[r] = exp2f((E1[r] - m[r]) * L2E);
            ps[r] = p0[r] + p1[r];
        }
#pragma unroll
        for (int r = 0; r < 4; r++) {
#pragma unroll
            for (int msk = 1; msk <= 8; msk <<= 1)
                ps[r] += __shfl_xor(ps[r], msk);
            lsum[r] += ps[r];
        }
        // ---- P -> bf16 -> LDS (wave-synchronous round trip to A-frag layout) ----
#pragma unroll
        for (int r = 0; r < 4; r++) {
            pl[(lg * 4 + r) * 32 + lr] = f2bf(p0[r]);
            pl[(lg * 4 + r) * 32 + 16 + lr] = f2bf(p1[r]);
        }
        asm volatile("s_waitcnt lgkmcnt(0)" ::: "memory");
        s16x8 pf = *(const s16x8*)(pl + lr * 32 + lg * 8);
        // ---- PV: O^T += P * V^T (16 independent accumulator chains) ----
#pragma unroll
        for (int ct = 0; ct < 16; ct++)
            O[ct] = mfma16(pf, vf[ct], O[ct]);
    }
    // ---- epilogue: out[b][c][i] = gamma * O/l + x ----
    float g = gamma[0];
    float rl[4];
#pragma unroll
    for (int r = 0; r < 4; r++) rl[r] = g / lsum[r];
    const float* xb = x + (size_t)b * Cc * Nn;
    float* ob = out + (size_t)b * Cc * Nn;
#pragma unroll
    for (int ct = 0; ct < 16; ct++) {
        size_t off = (size_t)(ct * 16 + lr) * Nn + i0 + lg * 4;
        float4 xv = *(const float4*)(xb + off);
        float4 o4;
        o4.x = O[ct][0] * rl[0] + xv.x;
        o4.y = O[ct][1] * rl[1] + xv.y;
        o4.z = O[ct][2] * rl[2] + xv.z;
        o4.w = O[ct][3] * rl[3] + xv.w;
        *(float4*)(ob + off) = o4;
    }
}

extern "C" void kernel_launch(void* const* d_in, const int* in_sizes, int n_in,
                              void* d_out, int out_size, void* d_ws, size_t ws_size,
                              hipStream_t stream) {
    (void)in_sizes; (void)n_in; (void)out_size; (void)ws_size;
    const float* x     = (const float*)d_in[0];
    const float* Wq    = (const float*)d_in[1];
    const float* bq    = (const float*)d_in[2];
    const float* Wk    = (const float*)d_in[3];
    const float* bk    = (const float*)d_in[4];
    const float* Wv    = (const float*)d_in[5];
    const float* bv    = (const float*)d_in[6];
    const float* gamma = (const float*)d_in[7];
    float* out = (float*)d_out;

    // workspace layout (bf16 elements): xT | Wbf | qT | kT | v  (~34 MB total)
    unsigned short* xT  = (unsigned short*)d_ws;
    unsigned short* Wbf = xT + (size_t)Bb * Nn * Cc;
    unsigned short* qT  = Wbf + 3 * Cc * Cc;
    unsigned short* kT  = qT + (size_t)Bb * Nn * Cc;
    unsigned short* vv  = kT + (size_t)Bb * Nn * Cc;

    hipLaunchKernelGGL(prep_w, dim3(96), dim3(256), 0, stream, Wq, Wk, Wv, Wbf);
    hipLaunchKernelGGL(transpose_x, dim3(Nn / 64, Cc / 64, Bb), dim3(256), 0, stream, x, xT);
    hipLaunchKernelGGL(proj, dim3(Nn / 64, 3, Bb), dim3(256), 0, stream,
                       xT, Wbf, bq, bk, bv, qT, kT, vv);
    hipLaunchKernelGGL(attn, dim3(Nn / 64, Bb), dim3(256), 0, stream,
                       qT, kT, vv, x, gamma, out);
}